// Round 1
// baseline (772.213 us; speedup 1.0000x reference)
//
#include <hip/hip_runtime.h>
#include <hip/hip_bf16.h>
#include <cstddef>

// ---------------------------------------------------------------------------
// GCN 2-layer forward, fp32.
//  h1 = relu(Agg(x @ W1) + b1);  out = log_softmax(Agg(h1 @ W2) + b2)
//  Agg(z)[i] = dinv[i]^2 * z[i] + sum_{e: col[e]==i} dinv[row]*w*dinv[i] * z[row]
// Strategy: build CSR (by target col) in-launch, then per-node register
// accumulation (no float atomics on the feature arrays).
// ---------------------------------------------------------------------------

#define DIN 256
#define DH  128
#define DOUT 64

__global__ void init_kernel(float* __restrict__ deg, int* __restrict__ cnt, int n) {
    int i = blockIdx.x * blockDim.x + threadIdx.x;
    if (i < n) { deg[i] = 1.0f; cnt[i] = 0; }   // self-loop weight 1
}

__global__ void count_kernel(const int* __restrict__ col, const float* __restrict__ w,
                             float* __restrict__ deg, int* __restrict__ cnt, int E) {
    int e = blockIdx.x * blockDim.x + threadIdx.x;
    if (e < E) {
        int c = col[e];
        atomicAdd(&deg[c], w[e]);
        atomicAdd(&cnt[c], 1);
    }
}

__global__ void dinv_kernel(const float* __restrict__ deg, float* __restrict__ dinv, int n) {
    int i = blockIdx.x * blockDim.x + threadIdx.x;
    if (i < n) {
        float d = deg[i];
        dinv[i] = (d > 0.0f) ? rsqrtf(d) : 0.0f;
    }
}

// Exclusive scan of cnt[0..n) -> rowptr[0..n], single block of 1024 threads.
// Also zeroes cnt for reuse as the fill cursor.
__global__ void scan_kernel(int* __restrict__ cnt, int* __restrict__ rowptr, int n) {
    __shared__ int sums[1024];
    int tid = threadIdx.x;
    int chunk = (n + 1023) >> 10;
    int s0 = tid * chunk;
    int s1 = min(s0 + chunk, n);
    int s = 0;
    for (int i = s0; i < s1; ++i) s += cnt[i];
    sums[tid] = s;
    __syncthreads();
    // Hillis-Steele inclusive scan
    for (int off = 1; off < 1024; off <<= 1) {
        int v = (tid >= off) ? sums[tid - off] : 0;
        __syncthreads();
        sums[tid] += v;
        __syncthreads();
    }
    int base = (tid == 0) ? 0 : sums[tid - 1];
    int run = base;
    for (int i = s0; i < s1; ++i) {
        rowptr[i] = run;
        run += cnt[i];
        cnt[i] = 0;           // reset for fill kernel
    }
    if (tid == 1023) rowptr[n] = sums[1023];
}

__global__ void fill_kernel(const int* __restrict__ row, const int* __restrict__ col,
                            const float* __restrict__ w, const float* __restrict__ dinv,
                            const int* __restrict__ rowptr, int* __restrict__ cursor,
                            int* __restrict__ src, float* __restrict__ wn, int E) {
    int e = blockIdx.x * blockDim.x + threadIdx.x;
    if (e < E) {
        int c = col[e];
        int r = row[e];
        int p = rowptr[c] + atomicAdd(&cursor[c], 1);
        src[p] = r;
        wn[p] = dinv[r] * w[e] * dinv[c];
    }
}

// C[N,M] = A[N,K] @ B[K,M].  BM=64 rows/block, full M width, BK=32.
// 256 threads, micro-tile 4 rows x (M/16) cols per thread.
template <int K, int M>
__launch_bounds__(256)
__global__ void gemm_kernel(const float* __restrict__ A, const float* __restrict__ B,
                            float* __restrict__ C, int N) {
    constexpr int BM = 64, BK = 32;
    constexpr int TN = M / 16;                    // 8 (M=128) or 4 (M=64)
    __shared__ float As[BK][BM + 4];
    __shared__ float Bs[BK][M + 4];
    const int tid = threadIdx.x;
    const int row0 = blockIdx.x * BM;
    const int ty = tid >> 4, tx = tid & 15;
    const int m0 = ty * 4;
    const int n0 = tx * TN;

    float acc[4][TN];
#pragma unroll
    for (int i = 0; i < 4; ++i)
#pragma unroll
        for (int j = 0; j < TN; ++j) acc[i][j] = 0.0f;

    for (int k0 = 0; k0 < K; k0 += BK) {
        // A tile: 64 rows x 32 k = 512 float4; 2 per thread, transposed into As[k][m]
#pragma unroll
        for (int l = 0; l < 2; ++l) {
            int q = tid + l * 256;
            int r = q >> 3;              // row in tile (8 float4 per row)
            int kp = (q & 7) * 4;
            int grow = row0 + r;
            float4 v = make_float4(0.f, 0.f, 0.f, 0.f);
            if (grow < N) v = *(const float4*)&A[(size_t)grow * K + k0 + kp];
            As[kp + 0][r] = v.x; As[kp + 1][r] = v.y;
            As[kp + 2][r] = v.z; As[kp + 3][r] = v.w;
        }
        // B tile: 32 x M
        constexpr int BQ = (BK * M / 4) / 256;   // 4 (M=128) or 2 (M=64)
#pragma unroll
        for (int l = 0; l < BQ; ++l) {
            int q = tid + l * 256;
            int kr = q / (M / 4);
            int cp = (q % (M / 4)) * 4;
            *(float4*)&Bs[kr][cp] = *(const float4*)&B[(size_t)(k0 + kr) * M + cp];
        }
        __syncthreads();
#pragma unroll
        for (int kk = 0; kk < BK; ++kk) {
            float4 a = *(const float4*)&As[kk][m0];
            float av[4] = {a.x, a.y, a.z, a.w};
            float bv[TN];
#pragma unroll
            for (int j = 0; j < TN; j += 4) {
                float4 b = *(const float4*)&Bs[kk][n0 + j];
                bv[j] = b.x; bv[j + 1] = b.y; bv[j + 2] = b.z; bv[j + 3] = b.w;
            }
#pragma unroll
            for (int i = 0; i < 4; ++i)
#pragma unroll
                for (int j = 0; j < TN; ++j)
                    acc[i][j] += av[i] * bv[j];
        }
        __syncthreads();
    }
#pragma unroll
    for (int i = 0; i < 4; ++i) {
        int gr = row0 + m0 + i;
        if (gr < N) {
#pragma unroll
            for (int j = 0; j < TN; j += 4) {
                *(float4*)&C[(size_t)gr * M + n0 + j] =
                    make_float4(acc[i][j], acc[i][j + 1], acc[i][j + 2], acc[i][j + 3]);
            }
        }
    }
}

// Layer-1 aggregation: one block (D threads) per node, relu(agg + b).
template <int D>
__global__ void agg_relu_kernel(const float* __restrict__ xw, const int* __restrict__ rowptr,
                                const int* __restrict__ src, const float* __restrict__ wn,
                                const float* __restrict__ dinv, const float* __restrict__ bias,
                                float* __restrict__ out, int n) {
    int i = blockIdx.x;
    int t = threadIdx.x;
    float di = dinv[i];
    float acc = di * di * xw[(size_t)i * D + t];
    int p1 = rowptr[i + 1];
    for (int p = rowptr[i]; p < p1; ++p) {
        int r = src[p];
        float c = wn[p];
        acc += c * xw[(size_t)r * D + t];
    }
    acc += bias[t];
    out[(size_t)i * D + t] = fmaxf(acc, 0.0f);
}

// Layer-2 aggregation fused with log_softmax: one wave (64 threads) per node.
__global__ void agg_lsm_kernel(const float* __restrict__ xw, const int* __restrict__ rowptr,
                               const int* __restrict__ src, const float* __restrict__ wn,
                               const float* __restrict__ dinv, const float* __restrict__ bias,
                               float* __restrict__ out, int n) {
    int i = blockIdx.x;
    int t = threadIdx.x;            // 0..63
    float di = dinv[i];
    float acc = di * di * xw[(size_t)i * DOUT + t];
    int p1 = rowptr[i + 1];
    for (int p = rowptr[i]; p < p1; ++p) {
        acc += wn[p] * xw[(size_t)src[p] * DOUT + t];
    }
    acc += bias[t];
    // log_softmax across the 64 lanes (one wave)
    float m = acc;
#pragma unroll
    for (int off = 32; off > 0; off >>= 1) m = fmaxf(m, __shfl_xor(m, off));
    float e = expf(acc - m);
    float s = e;
#pragma unroll
    for (int off = 32; off > 0; off >>= 1) s += __shfl_xor(s, off);
    out[(size_t)i * DOUT + t] = acc - m - logf(s);
}

extern "C" void kernel_launch(void* const* d_in, const int* in_sizes, int n_in,
                              void* d_out, int out_size, void* d_ws, size_t ws_size,
                              hipStream_t stream) {
    const float* x  = (const float*)d_in[0];
    const int*   ei = (const int*)d_in[1];
    const float* ew = (const float*)d_in[2];
    const float* W1 = (const float*)d_in[3];
    const float* b1 = (const float*)d_in[4];
    const float* W2 = (const float*)d_in[5];
    const float* b2 = (const float*)d_in[6];
    float* out = (float*)d_out;

    const int n = in_sizes[0] / DIN;      // 50000
    const int E = in_sizes[2];            // 1600000
    const int* row = ei;                  // edge_index[0]
    const int* col = ei + E;              // edge_index[1]

    // workspace carve-out (256B aligned)
    char* p = (char*)d_ws;
    auto alloc = [&](size_t bytes) -> void* {
        void* r = (void*)p;
        p += (bytes + 255) & ~(size_t)255;
        return r;
    };
    float* deg    = (float*)alloc((size_t)n * 4);
    float* dinv   = (float*)alloc((size_t)n * 4);
    int*   cnt    = (int*)  alloc((size_t)n * 4);        // count, then fill cursor
    int*   rowptr = (int*)  alloc((size_t)(n + 1) * 4);
    int*   srcv   = (int*)  alloc((size_t)E * 4);
    float* wn     = (float*)alloc((size_t)E * 4);
    float* xw1    = (float*)alloc((size_t)n * DH * 4);   // reused as xw2 after agg1
    float* h1     = (float*)alloc((size_t)n * DH * 4);
    float* xw2    = xw1;

    const int nb_n = (n + 255) / 256;
    const int nb_e = (E + 255) / 256;
    const int nb_g = (n + 63) / 64;

    init_kernel<<<nb_n, 256, 0, stream>>>(deg, cnt, n);
    count_kernel<<<nb_e, 256, 0, stream>>>(col, ew, deg, cnt, E);
    dinv_kernel<<<nb_n, 256, 0, stream>>>(deg, dinv, n);
    scan_kernel<<<1, 1024, 0, stream>>>(cnt, rowptr, n);
    fill_kernel<<<nb_e, 256, 0, stream>>>(row, col, ew, dinv, rowptr, cnt, srcv, wn, E);

    gemm_kernel<DIN, DH><<<nb_g, 256, 0, stream>>>(x, W1, xw1, n);
    agg_relu_kernel<DH><<<n, DH, 0, stream>>>(xw1, rowptr, srcv, wn, dinv, b1, h1, n);
    gemm_kernel<DH, DOUT><<<nb_g, 256, 0, stream>>>(h1, W2, xw2, n);
    agg_lsm_kernel<<<n, DOUT, 0, stream>>>(xw2, rowptr, srcv, wn, dinv, b2, out, n);
}

// Round 2
// 600.908 us; speedup vs baseline: 1.2851x; 1.2851x over previous
//
#include <hip/hip_runtime.h>
#include <hip/hip_bf16.h>
#include <cstddef>

// ---------------------------------------------------------------------------
// GCN 2-layer forward.
//  h1 = relu(Agg(x @ W1) + b1);  out = log_softmax(Agg(h1 @ W2) + b2)
//  Agg(z)[i] = dinv[i]^2 * z[i] + sum_{e: col[e]==i} dinv[row]*w*dinv[i] * z[row]
// Round 2: bf16 gather tables (xw1/xw2), int2-packed CSR edges, 4-way
// unrolled gathers for MLP. Accumulation fp32.
// ---------------------------------------------------------------------------

#define DIN 256
#define DH  128
#define DOUT 64

__device__ __forceinline__ float bflo(unsigned u) { return __uint_as_float(u << 16); }
__device__ __forceinline__ float bfhi(unsigned u) { return __uint_as_float(u & 0xffff0000u); }
__device__ __forceinline__ unsigned short f2bf(float f) {
    unsigned u = __float_as_uint(f);
    unsigned r = (u + 0x7fffu + ((u >> 16) & 1u)) >> 16;   // round-nearest-even
    return (unsigned short)r;
}

__global__ void init_kernel(float* __restrict__ deg, int* __restrict__ cnt, int n) {
    int i = blockIdx.x * blockDim.x + threadIdx.x;
    if (i < n) { deg[i] = 1.0f; cnt[i] = 0; }   // self-loop weight 1
}

__global__ void count_kernel(const int* __restrict__ col, const float* __restrict__ w,
                             float* __restrict__ deg, int* __restrict__ cnt, int E) {
    int e = blockIdx.x * blockDim.x + threadIdx.x;
    if (e < E) {
        int c = col[e];
        atomicAdd(&deg[c], w[e]);
        atomicAdd(&cnt[c], 1);
    }
}

__global__ void dinv_kernel(const float* __restrict__ deg, float* __restrict__ dinv, int n) {
    int i = blockIdx.x * blockDim.x + threadIdx.x;
    if (i < n) {
        float d = deg[i];
        dinv[i] = (d > 0.0f) ? rsqrtf(d) : 0.0f;
    }
}

// Exclusive scan of cnt[0..n) -> rowptr[0..n], single block of 1024 threads.
// Also zeroes cnt for reuse as the fill cursor.
__global__ void scan_kernel(int* __restrict__ cnt, int* __restrict__ rowptr, int n) {
    __shared__ int sums[1024];
    int tid = threadIdx.x;
    int chunk = (n + 1023) >> 10;
    int s0 = tid * chunk;
    int s1 = min(s0 + chunk, n);
    int s = 0;
    for (int i = s0; i < s1; ++i) s += cnt[i];
    sums[tid] = s;
    __syncthreads();
    for (int off = 1; off < 1024; off <<= 1) {
        int v = (tid >= off) ? sums[tid - off] : 0;
        __syncthreads();
        sums[tid] += v;
        __syncthreads();
    }
    int base = (tid == 0) ? 0 : sums[tid - 1];
    int run = base;
    for (int i = s0; i < s1; ++i) {
        rowptr[i] = run;
        run += cnt[i];
        cnt[i] = 0;           // reset for fill kernel
    }
    if (tid == 1023) rowptr[n] = sums[1023];
}

// Build CSR: edge[p] = (src_node, bitcast(norm_weight))
__global__ void fill_kernel(const int* __restrict__ row, const int* __restrict__ col,
                            const float* __restrict__ w, const float* __restrict__ dinv,
                            const int* __restrict__ rowptr, int* __restrict__ cursor,
                            int2* __restrict__ edge, int E) {
    int e = blockIdx.x * blockDim.x + threadIdx.x;
    if (e < E) {
        int c = col[e];
        int r = row[e];
        int p = rowptr[c] + atomicAdd(&cursor[c], 1);
        edge[p] = make_int2(r, __float_as_int(dinv[r] * w[e] * dinv[c]));
    }
}

// C[N,M] = A[N,K] @ B[K,M], fp32 compute, bf16 output.
// BM=64 rows/block, full M width, BK=32; 256 threads, 4 x (M/16) micro-tile.
template <int K, int M>
__launch_bounds__(256)
__global__ void gemm_kernel(const float* __restrict__ A, const float* __restrict__ B,
                            unsigned short* __restrict__ C, int N) {
    constexpr int BM = 64, BK = 32;
    constexpr int TN = M / 16;                    // 8 (M=128) or 4 (M=64)
    __shared__ float As[BK][BM + 4];
    __shared__ float Bs[BK][M + 4];
    const int tid = threadIdx.x;
    const int row0 = blockIdx.x * BM;
    const int ty = tid >> 4, tx = tid & 15;
    const int m0 = ty * 4;
    const int n0 = tx * TN;

    float acc[4][TN];
#pragma unroll
    for (int i = 0; i < 4; ++i)
#pragma unroll
        for (int j = 0; j < TN; ++j) acc[i][j] = 0.0f;

    for (int k0 = 0; k0 < K; k0 += BK) {
#pragma unroll
        for (int l = 0; l < 2; ++l) {
            int q = tid + l * 256;
            int r = q >> 3;              // 8 float4 per 32-wide k row
            int kp = (q & 7) * 4;
            int grow = row0 + r;
            float4 v = make_float4(0.f, 0.f, 0.f, 0.f);
            if (grow < N) v = *(const float4*)&A[(size_t)grow * K + k0 + kp];
            As[kp + 0][r] = v.x; As[kp + 1][r] = v.y;
            As[kp + 2][r] = v.z; As[kp + 3][r] = v.w;
        }
        constexpr int BQ = (BK * M / 4) / 256;   // 4 (M=128) or 2 (M=64)
#pragma unroll
        for (int l = 0; l < BQ; ++l) {
            int q = tid + l * 256;
            int kr = q / (M / 4);
            int cp = (q % (M / 4)) * 4;
            *(float4*)&Bs[kr][cp] = *(const float4*)&B[(size_t)(k0 + kr) * M + cp];
        }
        __syncthreads();
#pragma unroll
        for (int kk = 0; kk < BK; ++kk) {
            float4 a = *(const float4*)&As[kk][m0];
            float av[4] = {a.x, a.y, a.z, a.w};
            float bv[TN];
#pragma unroll
            for (int j = 0; j < TN; j += 4) {
                float4 b = *(const float4*)&Bs[kk][n0 + j];
                bv[j] = b.x; bv[j + 1] = b.y; bv[j + 2] = b.z; bv[j + 3] = b.w;
            }
#pragma unroll
            for (int i = 0; i < 4; ++i)
#pragma unroll
                for (int j = 0; j < TN; ++j)
                    acc[i][j] += av[i] * bv[j];
        }
        __syncthreads();
    }
#pragma unroll
    for (int i = 0; i < 4; ++i) {
        int gr = row0 + m0 + i;
        if (gr < N) {
#pragma unroll
            for (int j = 0; j < TN; j += 4) {
                ushort4 s;
                s.x = f2bf(acc[i][j]);     s.y = f2bf(acc[i][j + 1]);
                s.z = f2bf(acc[i][j + 2]); s.w = f2bf(acc[i][j + 3]);
                *(ushort4*)&C[(size_t)gr * M + n0 + j] = s;
            }
        }
    }
}

// Layer-1 aggregation: 1 wave per node (4 nodes / 256-thread block).
// xw is bf16 [n][128] read as uint (bf16x2) per lane; 4-way unrolled gathers.
__launch_bounds__(256)
__global__ void agg1_kernel(const unsigned* __restrict__ xw,       // bf16x2 [n][64]
                            const int* __restrict__ rowptr,
                            const int2* __restrict__ edge,
                            const float* __restrict__ dinv,
                            const float* __restrict__ bias,        // fp32 [128]
                            float* __restrict__ out, int n) {      // fp32 [n][128]
    int node = blockIdx.x * 4 + (threadIdx.x >> 6);
    if (node >= n) return;
    int lane = threadIdx.x & 63;
    float di = dinv[node];
    unsigned u = xw[(size_t)node * 64 + lane];
    float accx = di * di * bflo(u);
    float accy = di * di * bfhi(u);
    int p = rowptr[node], p1 = rowptr[node + 1];
    for (; p + 4 <= p1; p += 4) {
        int2 e0 = edge[p], e1 = edge[p + 1], e2 = edge[p + 2], e3 = edge[p + 3];
        unsigned v0 = xw[(size_t)e0.x * 64 + lane];
        unsigned v1 = xw[(size_t)e1.x * 64 + lane];
        unsigned v2 = xw[(size_t)e2.x * 64 + lane];
        unsigned v3 = xw[(size_t)e3.x * 64 + lane];
        float w0 = __int_as_float(e0.y), w1 = __int_as_float(e1.y);
        float w2 = __int_as_float(e2.y), w3 = __int_as_float(e3.y);
        accx += w0 * bflo(v0) + w1 * bflo(v1) + w2 * bflo(v2) + w3 * bflo(v3);
        accy += w0 * bfhi(v0) + w1 * bfhi(v1) + w2 * bfhi(v2) + w3 * bfhi(v3);
    }
    for (; p < p1; ++p) {
        int2 e0 = edge[p];
        unsigned v0 = xw[(size_t)e0.x * 64 + lane];
        float w0 = __int_as_float(e0.y);
        accx += w0 * bflo(v0);
        accy += w0 * bfhi(v0);
    }
    float2 b = ((const float2*)bias)[lane];
    accx = fmaxf(accx + b.x, 0.0f);
    accy = fmaxf(accy + b.y, 0.0f);
    ((float2*)out)[(size_t)node * 64 + lane] = make_float2(accx, accy);
}

// Layer-2 aggregation fused with log_softmax: 1 wave per node, lanes split
// into two half-waves each processing a different edge (2 edges per step,
// x4 unroll = 8 in flight). xw is bf16 [n][64] read as uint (bf16x2).
__launch_bounds__(256)
__global__ void agg2_kernel(const unsigned* __restrict__ xw,       // bf16x2 [n][32]
                            const int* __restrict__ rowptr,
                            const int2* __restrict__ edge,
                            const float* __restrict__ dinv,
                            const float* __restrict__ bias,        // fp32 [64]
                            float* __restrict__ out, int n) {      // fp32 [n][64]
    int node = blockIdx.x * 4 + (threadIdx.x >> 6);
    if (node >= n) return;
    int lane = threadIdx.x & 63;
    int half = lane >> 5;         // which edge of the pair this lane handles
    int sub  = lane & 31;         // feature pair index (features 2*sub, 2*sub+1)
    float accx = 0.0f, accy = 0.0f;
    if (half == 0) {
        float di = dinv[node];
        unsigned u = xw[(size_t)node * 32 + sub];
        accx = di * di * bflo(u);
        accy = di * di * bfhi(u);
    }
    int p = rowptr[node], p1 = rowptr[node + 1];
    for (; p + 8 <= p1; p += 8) {
        int2 e0 = edge[p + half],     e1 = edge[p + 2 + half];
        int2 e2 = edge[p + 4 + half], e3 = edge[p + 6 + half];
        unsigned v0 = xw[(size_t)e0.x * 32 + sub];
        unsigned v1 = xw[(size_t)e1.x * 32 + sub];
        unsigned v2 = xw[(size_t)e2.x * 32 + sub];
        unsigned v3 = xw[(size_t)e3.x * 32 + sub];
        float w0 = __int_as_float(e0.y), w1 = __int_as_float(e1.y);
        float w2 = __int_as_float(e2.y), w3 = __int_as_float(e3.y);
        accx += w0 * bflo(v0) + w1 * bflo(v1) + w2 * bflo(v2) + w3 * bflo(v3);
        accy += w0 * bfhi(v0) + w1 * bfhi(v1) + w2 * bfhi(v2) + w3 * bfhi(v3);
    }
    for (; p + 2 <= p1; p += 2) {
        int2 e0 = edge[p + half];
        unsigned v0 = xw[(size_t)e0.x * 32 + sub];
        float w0 = __int_as_float(e0.y);
        accx += w0 * bflo(v0);
        accy += w0 * bfhi(v0);
    }
    if (p < p1 && half == 0) {
        int2 e0 = edge[p];
        unsigned v0 = xw[(size_t)e0.x * 32 + sub];
        float w0 = __int_as_float(e0.y);
        accx += w0 * bflo(v0);
        accy += w0 * bfhi(v0);
    }
    // combine the two half-wave partial sums (both halves end up with totals)
    accx += __shfl_xor(accx, 32);
    accy += __shfl_xor(accy, 32);
    float2 b = ((const float2*)bias)[sub];
    accx += b.x; accy += b.y;
    // log_softmax over 64 features = 32 sublanes x 2 (reduce within half-wave)
    float m = fmaxf(accx, accy);
#pragma unroll
    for (int off = 16; off > 0; off >>= 1) m = fmaxf(m, __shfl_xor(m, off));
    float s = __expf(accx - m) + __expf(accy - m);
#pragma unroll
    for (int off = 16; off > 0; off >>= 1) s += __shfl_xor(s, off);
    float lse = m + __logf(s);
    if (half == 0) {
        ((float2*)out)[(size_t)node * 32 + sub] = make_float2(accx - lse, accy - lse);
    }
}

extern "C" void kernel_launch(void* const* d_in, const int* in_sizes, int n_in,
                              void* d_out, int out_size, void* d_ws, size_t ws_size,
                              hipStream_t stream) {
    const float* x  = (const float*)d_in[0];
    const int*   ei = (const int*)d_in[1];
    const float* ew = (const float*)d_in[2];
    const float* W1 = (const float*)d_in[3];
    const float* b1 = (const float*)d_in[4];
    const float* W2 = (const float*)d_in[5];
    const float* b2 = (const float*)d_in[6];
    float* out = (float*)d_out;

    const int n = in_sizes[0] / DIN;      // 50000
    const int E = in_sizes[2];            // 1600000
    const int* row = ei;                  // edge_index[0] (source)
    const int* col = ei + E;              // edge_index[1] (target)

    char* p = (char*)d_ws;
    auto alloc = [&](size_t bytes) -> void* {
        void* r = (void*)p;
        p += (bytes + 255) & ~(size_t)255;
        return r;
    };
    float* deg    = (float*)alloc((size_t)n * 4);
    float* dinv   = (float*)alloc((size_t)n * 4);
    int*   cnt    = (int*)  alloc((size_t)n * 4);        // count, then fill cursor
    int*   rowptr = (int*)  alloc((size_t)(n + 1) * 4);
    int2*  edge   = (int2*) alloc((size_t)E * 8);
    unsigned short* xw1 = (unsigned short*)alloc((size_t)n * DH * 2);  // bf16; reused as xw2
    float* h1     = (float*)alloc((size_t)n * DH * 4);
    unsigned short* xw2 = xw1;

    const int nb_n = (n + 255) / 256;
    const int nb_e = (E + 255) / 256;
    const int nb_g = (n + 63) / 64;
    const int nb_a = (n + 3) / 4;

    init_kernel<<<nb_n, 256, 0, stream>>>(deg, cnt, n);
    count_kernel<<<nb_e, 256, 0, stream>>>(col, ew, deg, cnt, E);
    dinv_kernel<<<nb_n, 256, 0, stream>>>(deg, dinv, n);
    scan_kernel<<<1, 1024, 0, stream>>>(cnt, rowptr, n);
    fill_kernel<<<nb_e, 256, 0, stream>>>(row, col, ew, dinv, rowptr, cnt, edge, E);

    gemm_kernel<DIN, DH><<<nb_g, 256, 0, stream>>>(x, W1, xw1, n);
    agg1_kernel<<<nb_a, 256, 0, stream>>>((const unsigned*)xw1, rowptr, edge, dinv, b1, h1, n);
    gemm_kernel<DH, DOUT><<<nb_g, 256, 0, stream>>>(h1, W2, xw2, n);
    agg2_kernel<<<nb_a, 256, 0, stream>>>((const unsigned*)xw2, rowptr, edge, dinv, b2, out, n);
}

// Round 3
// 336.306 us; speedup vs baseline: 2.2962x; 1.7868x over previous
//
#include <hip/hip_runtime.h>
#include <hip/hip_bf16.h>
#include <cstddef>

// ---------------------------------------------------------------------------
// GCN 2-layer forward.
//  h1 = relu(Agg(x @ W1) + b1);  out = log_softmax(Agg(h1 @ W2) + b2)
//  Agg(z)[i] = dinv[i]^2 * z[i] + sum_{e: col[e]==i} dinv[row]*w*dinv[i] * z[row]
// Round 3: CSR build WITHOUT global atomics (round-2 profile: 3.2M device
// atomics in count_kernel = 145us, ~64B line write-through each). Two-level
// bucket partition with LDS histograms + LDS cursors instead.
// ---------------------------------------------------------------------------

#define DIN 256
#define DH  128
#define DOUT 64
#define NPB 100        // nodes per bucket (50000/100 = 500 buckets)
#define NBMAX 512      // max buckets (shared-array size)

__device__ __forceinline__ float bflo(unsigned u) { return __uint_as_float(u << 16); }
__device__ __forceinline__ float bfhi(unsigned u) { return __uint_as_float(u & 0xffff0000u); }
__device__ __forceinline__ unsigned short f2bf(float f) {
    unsigned u = __float_as_uint(f);
    unsigned r = (u + 0x7fffu + ((u >> 16) & 1u)) >> 16;   // round-nearest-even
    return (unsigned short)r;
}

// Pass 1: per-block bucket histogram (LDS), write bh[p][NB].
__launch_bounds__(256)
__global__ void hist_kernel(const int* __restrict__ col, int* __restrict__ bh,
                            int E, int Ec, int NB) {
    __shared__ int hist[NBMAX];
    int p = blockIdx.x, t = threadIdx.x;
    for (int b = t; b < NB; b += 256) hist[b] = 0;
    __syncthreads();
    int s = p * Ec, e = min(s + Ec, E);
    for (int i = s + t; i < e; i += 256) atomicAdd(&hist[col[i] / NPB], 1);
    __syncthreads();
    for (int b = t; b < NB; b += 256) bh[p * NB + b] = hist[b];
}

// Pass 2: per-bucket column scan over blocks. bh[p][b] -> exclusive prefix
// (in place); btotal[b] = column total. One block (512 thr) per bucket.
__launch_bounds__(512)
__global__ void colscan_kernel(int* __restrict__ bh, int* __restrict__ btotal,
                               int P, int NB) {
    __shared__ int arr[512];
    int b = blockIdx.x, t = threadIdx.x;
    arr[t] = (t < P) ? bh[t * NB + b] : 0;
    __syncthreads();
    for (int off = 1; off < 512; off <<= 1) {
        int v = (t >= off) ? arr[t - off] : 0;
        __syncthreads();
        arr[t] += v;
        __syncthreads();
    }
    int excl = (t == 0) ? 0 : arr[t - 1];
    if (t < P) bh[t * NB + b] = excl;
    if (t == P - 1) btotal[b] = arr[t];
}

// Pass 2b: exclusive scan of btotal -> bbase[0..NB] (bbase[NB]=E); rowptr[n]=E.
__launch_bounds__(512)
__global__ void basescan_kernel(const int* __restrict__ btotal, int* __restrict__ bbase,
                                int* __restrict__ rowptr, int NB, int n, int E) {
    __shared__ int arr[512];
    int t = threadIdx.x;
    arr[t] = (t < NB) ? btotal[t] : 0;
    __syncthreads();
    for (int off = 1; off < 512; off <<= 1) {
        int v = (t >= off) ? arr[t - off] : 0;
        __syncthreads();
        arr[t] += v;
        __syncthreads();
    }
    int excl = (t == 0) ? 0 : arr[t - 1];
    if (t <= NB) bbase[t] = excl;
    if (t == 511) rowptr[n] = E;
}

// Pass 3: scatter edges into bucket-partitioned order via LDS cursors.
// part[pos] = (row | col_local<<16, w_bits). No global atomics.
__launch_bounds__(256)
__global__ void scatter_kernel(const int* __restrict__ row, const int* __restrict__ col,
                               const float* __restrict__ w, const int* __restrict__ bh,
                               const int* __restrict__ bbase, int2* __restrict__ part,
                               int E, int Ec, int NB) {
    __shared__ int cur[NBMAX];
    int p = blockIdx.x, t = threadIdx.x;
    for (int b = t; b < NB; b += 256) cur[b] = bbase[b] + bh[p * NB + b];
    __syncthreads();
    int s = p * Ec, e = min(s + Ec, E);
    for (int i = s + t; i < e; i += 256) {
        int c = col[i];
        int r = row[i];
        int b = c / NPB;
        int pos = atomicAdd(&cur[b], 1);          // LDS atomic
        part[pos] = make_int2(r | ((c - b * NPB) << 16), __float_as_int(w[i]));
    }
}

// Pass 4: one block per bucket. LDS histogram/scan over the bucket's 100
// nodes -> deg/dinv/rowptr; reorder edges to per-node CSR, folding in
// dinv[col] (local). final_e[q] = (row, w*dinv_col).
__launch_bounds__(256)
__global__ void bucket_csr_kernel(const int2* __restrict__ part, const int* __restrict__ bbase,
                                  float* __restrict__ dinv, int* __restrict__ rowptr,
                                  int2* __restrict__ final_e, int n) {
    __shared__ int   hist[NPB];
    __shared__ float wsum[NPB];
    __shared__ int   nbase[NPB];
    __shared__ int   cur[NPB];
    __shared__ float dvl[NPB];
    int b = blockIdx.x, t = threadIdx.x;
    if (t < NPB) { hist[t] = 0; wsum[t] = 0.0f; }
    __syncthreads();
    int s = bbase[b], e = bbase[b + 1];
    for (int i = s + t; i < e; i += 256) {
        int2 rec = part[i];
        int cl = rec.x >> 16;
        atomicAdd(&hist[cl], 1);
        atomicAdd(&wsum[cl], __int_as_float(rec.y));
    }
    __syncthreads();
    if (t == 0) {
        int run = 0;
        for (int k = 0; k < NPB; ++k) { nbase[k] = run; run += hist[k]; }
    }
    __syncthreads();
    if (t < NPB) {
        int node = b * NPB + t;
        float dv = rsqrtf(1.0f + wsum[t]);        // deg >= 1 (self-loop)
        dvl[t] = dv;
        if (node < n) {
            dinv[node] = dv;
            rowptr[node] = s + nbase[t];
        }
        cur[t] = nbase[t];
    }
    __syncthreads();
    for (int i = s + t; i < e; i += 256) {
        int2 rec = part[i];
        int cl = rec.x >> 16;
        int r = rec.x & 0xffff;
        float wv = __int_as_float(rec.y);
        int q = s + atomicAdd(&cur[cl], 1);       // LDS atomic
        final_e[q] = make_int2(r, __float_as_int(wv * dvl[cl]));
    }
}

// Pass 5: fold in dinv[row] (edge-parallel, in-place, dinv table is L2-hot).
__launch_bounds__(256)
__global__ void normw_kernel(int2* __restrict__ final_e, const float* __restrict__ dinv, int E) {
    int i = blockIdx.x * blockDim.x + threadIdx.x;
    if (i < E) {
        int2 rec = final_e[i];
        rec.y = __float_as_int(__int_as_float(rec.y) * dinv[rec.x]);
        final_e[i] = rec;
    }
}

// C[N,M] = A[N,K] @ B[K,M], fp32 compute, bf16 output.
template <int K, int M>
__launch_bounds__(256)
__global__ void gemm_kernel(const float* __restrict__ A, const float* __restrict__ B,
                            unsigned short* __restrict__ C, int N) {
    constexpr int BM = 64, BK = 32;
    constexpr int TN = M / 16;                    // 8 (M=128) or 4 (M=64)
    __shared__ float As[BK][BM + 4];
    __shared__ float Bs[BK][M + 4];
    const int tid = threadIdx.x;
    const int row0 = blockIdx.x * BM;
    const int ty = tid >> 4, tx = tid & 15;
    const int m0 = ty * 4;
    const int n0 = tx * TN;

    float acc[4][TN];
#pragma unroll
    for (int i = 0; i < 4; ++i)
#pragma unroll
        for (int j = 0; j < TN; ++j) acc[i][j] = 0.0f;

    for (int k0 = 0; k0 < K; k0 += BK) {
#pragma unroll
        for (int l = 0; l < 2; ++l) {
            int q = tid + l * 256;
            int r = q >> 3;
            int kp = (q & 7) * 4;
            int grow = row0 + r;
            float4 v = make_float4(0.f, 0.f, 0.f, 0.f);
            if (grow < N) v = *(const float4*)&A[(size_t)grow * K + k0 + kp];
            As[kp + 0][r] = v.x; As[kp + 1][r] = v.y;
            As[kp + 2][r] = v.z; As[kp + 3][r] = v.w;
        }
        constexpr int BQ = (BK * M / 4) / 256;
#pragma unroll
        for (int l = 0; l < BQ; ++l) {
            int q = tid + l * 256;
            int kr = q / (M / 4);
            int cp = (q % (M / 4)) * 4;
            *(float4*)&Bs[kr][cp] = *(const float4*)&B[(size_t)(k0 + kr) * M + cp];
        }
        __syncthreads();
#pragma unroll
        for (int kk = 0; kk < BK; ++kk) {
            float4 a = *(const float4*)&As[kk][m0];
            float av[4] = {a.x, a.y, a.z, a.w};
            float bv[TN];
#pragma unroll
            for (int j = 0; j < TN; j += 4) {
                float4 b = *(const float4*)&Bs[kk][n0 + j];
                bv[j] = b.x; bv[j + 1] = b.y; bv[j + 2] = b.z; bv[j + 3] = b.w;
            }
#pragma unroll
            for (int i = 0; i < 4; ++i)
#pragma unroll
                for (int j = 0; j < TN; ++j)
                    acc[i][j] += av[i] * bv[j];
        }
        __syncthreads();
    }
#pragma unroll
    for (int i = 0; i < 4; ++i) {
        int gr = row0 + m0 + i;
        if (gr < N) {
#pragma unroll
            for (int j = 0; j < TN; j += 4) {
                ushort4 s;
                s.x = f2bf(acc[i][j]);     s.y = f2bf(acc[i][j + 1]);
                s.z = f2bf(acc[i][j + 2]); s.w = f2bf(acc[i][j + 3]);
                *(ushort4*)&C[(size_t)gr * M + n0 + j] = s;
            }
        }
    }
}

// Layer-1 aggregation: 1 wave per node; bf16x2 gathers, 4-way unroll.
__launch_bounds__(256)
__global__ void agg1_kernel(const unsigned* __restrict__ xw,       // bf16x2 [n][64]
                            const int* __restrict__ rowptr,
                            const int2* __restrict__ edge,
                            const float* __restrict__ dinv,
                            const float* __restrict__ bias,        // fp32 [128]
                            float* __restrict__ out, int n) {      // fp32 [n][128]
    int node = blockIdx.x * 4 + (threadIdx.x >> 6);
    if (node >= n) return;
    int lane = threadIdx.x & 63;
    float di = dinv[node];
    unsigned u = xw[(size_t)node * 64 + lane];
    float accx = di * di * bflo(u);
    float accy = di * di * bfhi(u);
    int p = rowptr[node], p1 = rowptr[node + 1];
    for (; p + 4 <= p1; p += 4) {
        int2 e0 = edge[p], e1 = edge[p + 1], e2 = edge[p + 2], e3 = edge[p + 3];
        unsigned v0 = xw[(size_t)e0.x * 64 + lane];
        unsigned v1 = xw[(size_t)e1.x * 64 + lane];
        unsigned v2 = xw[(size_t)e2.x * 64 + lane];
        unsigned v3 = xw[(size_t)e3.x * 64 + lane];
        float w0 = __int_as_float(e0.y), w1 = __int_as_float(e1.y);
        float w2 = __int_as_float(e2.y), w3 = __int_as_float(e3.y);
        accx += w0 * bflo(v0) + w1 * bflo(v1) + w2 * bflo(v2) + w3 * bflo(v3);
        accy += w0 * bfhi(v0) + w1 * bfhi(v1) + w2 * bfhi(v2) + w3 * bfhi(v3);
    }
    for (; p < p1; ++p) {
        int2 e0 = edge[p];
        unsigned v0 = xw[(size_t)e0.x * 64 + lane];
        float w0 = __int_as_float(e0.y);
        accx += w0 * bflo(v0);
        accy += w0 * bfhi(v0);
    }
    float2 b = ((const float2*)bias)[lane];
    accx = fmaxf(accx + b.x, 0.0f);
    accy = fmaxf(accy + b.y, 0.0f);
    ((float2*)out)[(size_t)node * 64 + lane] = make_float2(accx, accy);
}

// Layer-2 aggregation fused with log_softmax: 1 wave/node, 2 edges per step
// (half-wave split), 4-way unroll.
__launch_bounds__(256)
__global__ void agg2_kernel(const unsigned* __restrict__ xw,       // bf16x2 [n][32]
                            const int* __restrict__ rowptr,
                            const int2* __restrict__ edge,
                            const float* __restrict__ dinv,
                            const float* __restrict__ bias,        // fp32 [64]
                            float* __restrict__ out, int n) {      // fp32 [n][64]
    int node = blockIdx.x * 4 + (threadIdx.x >> 6);
    if (node >= n) return;
    int lane = threadIdx.x & 63;
    int half = lane >> 5;
    int sub  = lane & 31;
    float accx = 0.0f, accy = 0.0f;
    if (half == 0) {
        float di = dinv[node];
        unsigned u = xw[(size_t)node * 32 + sub];
        accx = di * di * bflo(u);
        accy = di * di * bfhi(u);
    }
    int p = rowptr[node], p1 = rowptr[node + 1];
    for (; p + 8 <= p1; p += 8) {
        int2 e0 = edge[p + half],     e1 = edge[p + 2 + half];
        int2 e2 = edge[p + 4 + half], e3 = edge[p + 6 + half];
        unsigned v0 = xw[(size_t)e0.x * 32 + sub];
        unsigned v1 = xw[(size_t)e1.x * 32 + sub];
        unsigned v2 = xw[(size_t)e2.x * 32 + sub];
        unsigned v3 = xw[(size_t)e3.x * 32 + sub];
        float w0 = __int_as_float(e0.y), w1 = __int_as_float(e1.y);
        float w2 = __int_as_float(e2.y), w3 = __int_as_float(e3.y);
        accx += w0 * bflo(v0) + w1 * bflo(v1) + w2 * bflo(v2) + w3 * bflo(v3);
        accy += w0 * bfhi(v0) + w1 * bfhi(v1) + w2 * bfhi(v2) + w3 * bfhi(v3);
    }
    for (; p + 2 <= p1; p += 2) {
        int2 e0 = edge[p + half];
        unsigned v0 = xw[(size_t)e0.x * 32 + sub];
        float w0 = __int_as_float(e0.y);
        accx += w0 * bflo(v0);
        accy += w0 * bfhi(v0);
    }
    if (p < p1 && half == 0) {
        int2 e0 = edge[p];
        unsigned v0 = xw[(size_t)e0.x * 32 + sub];
        float w0 = __int_as_float(e0.y);
        accx += w0 * bflo(v0);
        accy += w0 * bfhi(v0);
    }
    accx += __shfl_xor(accx, 32);
    accy += __shfl_xor(accy, 32);
    float2 b = ((const float2*)bias)[sub];
    accx += b.x; accy += b.y;
    float m = fmaxf(accx, accy);
#pragma unroll
    for (int off = 16; off > 0; off >>= 1) m = fmaxf(m, __shfl_xor(m, off));
    float s = __expf(accx - m) + __expf(accy - m);
#pragma unroll
    for (int off = 16; off > 0; off >>= 1) s += __shfl_xor(s, off);
    float lse = m + __logf(s);
    if (half == 0) {
        ((float2*)out)[(size_t)node * 32 + sub] = make_float2(accx - lse, accy - lse);
    }
}

extern "C" void kernel_launch(void* const* d_in, const int* in_sizes, int n_in,
                              void* d_out, int out_size, void* d_ws, size_t ws_size,
                              hipStream_t stream) {
    const float* x  = (const float*)d_in[0];
    const int*   ei = (const int*)d_in[1];
    const float* ew = (const float*)d_in[2];
    const float* W1 = (const float*)d_in[3];
    const float* b1 = (const float*)d_in[4];
    const float* W2 = (const float*)d_in[5];
    const float* b2 = (const float*)d_in[6];
    float* out = (float*)d_out;

    const int n = in_sizes[0] / DIN;      // 50000
    const int E = in_sizes[2];            // 1600000
    const int* row = ei;                  // edge_index[0] (source)
    const int* col = ei + E;              // edge_index[1] (target)

    const int NB = (n + NPB - 1) / NPB;   // 500 buckets
    const int P  = NB;                    // partition blocks
    const int Ec = (E + P - 1) / P;       // 3200 edges/block

    char* ptr = (char*)d_ws;
    auto alloc = [&](size_t bytes) -> void* {
        void* r = (void*)ptr;
        ptr += (bytes + 255) & ~(size_t)255;
        return r;
    };
    int*   bh     = (int*)  alloc((size_t)P * NB * 4);       // 1 MB
    int*   btotal = (int*)  alloc((size_t)NB * 4);
    int*   bbase  = (int*)  alloc((size_t)(NB + 1) * 4);
    int*   rowptr = (int*)  alloc((size_t)(n + 1) * 4);
    float* dinv   = (float*)alloc((size_t)n * 4);
    int2*  edge   = (int2*) alloc((size_t)E * 8);            // final CSR edges
    unsigned short* xw1 = (unsigned short*)alloc((size_t)n * DH * 2);  // bf16
    // tail region: part (12.8MB, passes 3-4) then h1 (25.6MB, agg1+) — disjoint lifetimes
    char* tail = (char*)alloc((size_t)n * DH * 4);           // 25.6 MB
    int2*  part = (int2*)tail;
    float* h1   = (float*)tail;
    unsigned short* xw2 = xw1;

    const int nb_e = (E + 255) / 256;
    const int nb_g = (n + 63) / 64;
    const int nb_a = (n + 3) / 4;

    hist_kernel<<<P, 256, 0, stream>>>(col, bh, E, Ec, NB);
    colscan_kernel<<<NB, 512, 0, stream>>>(bh, btotal, P, NB);
    basescan_kernel<<<1, 512, 0, stream>>>(btotal, bbase, rowptr, NB, n, E);
    scatter_kernel<<<P, 256, 0, stream>>>(row, col, ew, bh, bbase, part, E, Ec, NB);
    bucket_csr_kernel<<<NB, 256, 0, stream>>>(part, bbase, dinv, rowptr, edge, n);
    normw_kernel<<<nb_e, 256, 0, stream>>>(edge, dinv, E);

    gemm_kernel<DIN, DH><<<nb_g, 256, 0, stream>>>(x, W1, xw1, n);
    agg1_kernel<<<nb_a, 256, 0, stream>>>((const unsigned*)xw1, rowptr, edge, dinv, b1, h1, n);
    gemm_kernel<DH, DOUT><<<nb_g, 256, 0, stream>>>(h1, W2, xw2, n);
    agg2_kernel<<<nb_a, 256, 0, stream>>>((const unsigned*)xw2, rowptr, edge, dinv, b2, out, n);
}

// Round 4
// 286.588 us; speedup vs baseline: 2.6945x; 1.1735x over previous
//
#include <hip/hip_runtime.h>
#include <hip/hip_bf16.h>
#include <cstddef>

// ---------------------------------------------------------------------------
// GCN 2-layer forward.
//  h1 = relu(Agg(x @ W1) + b1);  out = log_softmax(Agg(h1 @ W2) + b2)
//  Agg(z)[i] = dinv[i]^2 z[i] + sum_{e: col[e]==i} dinv[row] w dinv[i] z[row]
// Round 4:
//  * Gather tables pre-scaled by dinv in the GEMM epilogue:
//      out = dinv[c] * ( t[c] + sum_e w_e * t[r_e] ) + b,  t[i] = dinv[i]*(z@W)[i]
//    -> edges carry RAW w, normw pass eliminated.
//  * agg1: half-wave edge split (8 gathers in flight); agg2: quarter-wave.
//  * GEMMs via bf16 MFMA (16x16x32), LDS-staged, dinv-scaling fused epilogue.
// ---------------------------------------------------------------------------

#define DIN 256
#define DH  128
#define DOUT 64
#define NPB 100        // nodes per bucket (50000/100 = 500 buckets)
#define NBMAX 512      // max buckets (shared-array size)

typedef __bf16 bf16x8 __attribute__((ext_vector_type(8)));
typedef float f32x4 __attribute__((ext_vector_type(4)));

__device__ __forceinline__ float bflo(unsigned u) { return __uint_as_float(u << 16); }
__device__ __forceinline__ float bfhi(unsigned u) { return __uint_as_float(u & 0xffff0000u); }
__device__ __forceinline__ unsigned short f2bf(float f) {
    unsigned u = __float_as_uint(f);
    unsigned r = (u + 0x7fffu + ((u >> 16) & 1u)) >> 16;   // round-nearest-even
    return (unsigned short)r;
}

// Convert + transpose weights once: wt[n][k] = bf16(W[k][n]).
__global__ void prep_w_kernel(const float* __restrict__ W1, const float* __restrict__ W2,
                              unsigned short* __restrict__ wt1, unsigned short* __restrict__ wt2) {
    int i = blockIdx.x * 256 + threadIdx.x;
    if (i < DH * DIN) {                       // wt1 [128][256]
        int nn = i >> 8, k = i & 255;
        wt1[i] = f2bf(W1[k * DH + nn]);
    } else {
        int j = i - DH * DIN;
        if (j < DOUT * DH) {                  // wt2 [64][128]
            int nn = j >> 7, k = j & 127;
            wt2[j] = f2bf(W2[k * DOUT + nn]);
        }
    }
}

// Pass 1: per-block bucket histogram (LDS), write bh[p][NB].
__launch_bounds__(256)
__global__ void hist_kernel(const int* __restrict__ col, int* __restrict__ bh,
                            int E, int Ec, int NB) {
    __shared__ int hist[NBMAX];
    int p = blockIdx.x, t = threadIdx.x;
    for (int b = t; b < NB; b += 256) hist[b] = 0;
    __syncthreads();
    int s = p * Ec, e = min(s + Ec, E);
    for (int i = s + t; i < e; i += 256) atomicAdd(&hist[col[i] / NPB], 1);
    __syncthreads();
    for (int b = t; b < NB; b += 256) bh[p * NB + b] = hist[b];
}

// Pass 2: per-bucket column scan over blocks (exclusive, in place).
__launch_bounds__(512)
__global__ void colscan_kernel(int* __restrict__ bh, int* __restrict__ btotal,
                               int P, int NB) {
    __shared__ int arr[512];
    int b = blockIdx.x, t = threadIdx.x;
    arr[t] = (t < P) ? bh[t * NB + b] : 0;
    __syncthreads();
    for (int off = 1; off < 512; off <<= 1) {
        int v = (t >= off) ? arr[t - off] : 0;
        __syncthreads();
        arr[t] += v;
        __syncthreads();
    }
    int excl = (t == 0) ? 0 : arr[t - 1];
    if (t < P) bh[t * NB + b] = excl;
    if (t == P - 1) btotal[b] = arr[t];
}

// Pass 2b: exclusive scan of btotal -> bbase[0..NB]; rowptr[n]=E.
__launch_bounds__(512)
__global__ void basescan_kernel(const int* __restrict__ btotal, int* __restrict__ bbase,
                                int* __restrict__ rowptr, int NB, int n, int E) {
    __shared__ int arr[512];
    int t = threadIdx.x;
    arr[t] = (t < NB) ? btotal[t] : 0;
    __syncthreads();
    for (int off = 1; off < 512; off <<= 1) {
        int v = (t >= off) ? arr[t - off] : 0;
        __syncthreads();
        arr[t] += v;
        __syncthreads();
    }
    int excl = (t == 0) ? 0 : arr[t - 1];
    if (t <= NB) bbase[t] = excl;
    if (t == 511) rowptr[n] = E;
}

// Pass 3: scatter edges into bucket-partitioned order via LDS cursors.
// part[pos] = (row | col_local<<16, w_bits).
__launch_bounds__(256)
__global__ void scatter_kernel(const int* __restrict__ row, const int* __restrict__ col,
                               const float* __restrict__ w, const int* __restrict__ bh,
                               const int* __restrict__ bbase, int2* __restrict__ part,
                               int E, int Ec, int NB) {
    __shared__ int cur[NBMAX];
    int p = blockIdx.x, t = threadIdx.x;
    for (int b = t; b < NB; b += 256) cur[b] = bbase[b] + bh[p * NB + b];
    __syncthreads();
    int s = p * Ec, e = min(s + Ec, E);
    for (int i = s + t; i < e; i += 256) {
        int c = col[i];
        int r = row[i];
        int b = c / NPB;
        int pos = atomicAdd(&cur[b], 1);          // LDS atomic
        part[pos] = make_int2(r | ((c - b * NPB) << 16), __float_as_int(w[i]));
    }
}

// Pass 4: one block per bucket: per-node deg/dinv/rowptr + per-node CSR
// (edges keep RAW weight now; dinv folded via pre-scaled tables instead).
__launch_bounds__(256)
__global__ void bucket_csr_kernel(const int2* __restrict__ part, const int* __restrict__ bbase,
                                  float* __restrict__ dinv, int* __restrict__ rowptr,
                                  int2* __restrict__ final_e, int n) {
    __shared__ int   hist[NPB];
    __shared__ float wsum[NPB];
    __shared__ int   nbase[NPB];
    __shared__ int   cur[NPB];
    int b = blockIdx.x, t = threadIdx.x;
    if (t < NPB) { hist[t] = 0; wsum[t] = 0.0f; }
    __syncthreads();
    int s = bbase[b], e = bbase[b + 1];
    for (int i = s + t; i < e; i += 256) {
        int2 rec = part[i];
        int cl = rec.x >> 16;
        atomicAdd(&hist[cl], 1);
        atomicAdd(&wsum[cl], __int_as_float(rec.y));
    }
    __syncthreads();
    if (t == 0) {
        int run = 0;
        for (int k = 0; k < NPB; ++k) { nbase[k] = run; run += hist[k]; }
    }
    __syncthreads();
    if (t < NPB) {
        int node = b * NPB + t;
        if (node < n) {
            dinv[node] = rsqrtf(1.0f + wsum[t]);   // deg >= 1 (self-loop)
            rowptr[node] = s + nbase[t];
        }
        cur[t] = nbase[t];
    }
    __syncthreads();
    for (int i = s + t; i < e; i += 256) {
        int2 rec = part[i];
        int cl = rec.x >> 16;
        int q = s + atomicAdd(&cur[cl], 1);       // LDS atomic
        final_e[q] = make_int2(rec.x & 0xffff, rec.y);   // (src, raw w)
    }
}

// MFMA GEMM: C[r][:] = bf16( scale[r] * (A[r][:K] @ B) ), B given transposed
// bf16 as Wt[n][k] ([M][K]). Block: 64 rows x full M, 4 waves (wave = M/4 cols).
template <int K, int M>
__launch_bounds__(256)
__global__ void gemm_mfma_kernel(const float* __restrict__ A,
                                 const unsigned short* __restrict__ Wt,
                                 const float* __restrict__ scale,
                                 unsigned short* __restrict__ C, int N) {
    constexpr int BK = 64, LD = BK + 8;       // LDS k-stride (pad: 2-way-free banks)
    constexpr int WN = M / 4;                 // cols per wave
    constexpr int NT = WN / 16;               // 16x16 n-tiles per wave
    constexpr int CLD = M + 8;
    constexpr int SM = (64 * LD + M * LD) > (64 * CLD) ? (64 * LD + M * LD) : (64 * CLD);
    __shared__ unsigned short smem[SM];
    __shared__ float sdv[64];
    unsigned short* As = smem;                // [64][LD]
    unsigned short* Bs = smem + 64 * LD;      // [M][LD]

    const int tid = threadIdx.x;
    const int row0 = blockIdx.x * 64;
    const int lane = tid & 63;
    const int quad = lane >> 4, r16 = lane & 15;
    const int n0 = (tid >> 6) * WN;

    if (tid < 64) {
        int r = row0 + tid;
        sdv[tid] = (r < N) ? scale[r] : 0.0f;
    }

    f32x4 acc[4][NT];
#pragma unroll
    for (int mt = 0; mt < 4; ++mt)
#pragma unroll
        for (int nt = 0; nt < NT; ++nt)
            acc[mt][nt] = (f32x4){0.f, 0.f, 0.f, 0.f};

    for (int k0 = 0; k0 < K; k0 += BK) {
        // stage A: 64 rows x 64 k, fp32 -> bf16 (1024 float4, 4/thread)
#pragma unroll
        for (int j = 0; j < 4; ++j) {
            int idx = tid + j * 256;
            int m = idx >> 4;
            int q = idx & 15;
            int gr = row0 + m;
            float4 v = make_float4(0.f, 0.f, 0.f, 0.f);
            if (gr < N) v = *(const float4*)&A[(size_t)gr * K + k0 + q * 4];
            ushort4 s4;
            s4.x = f2bf(v.x); s4.y = f2bf(v.y); s4.z = f2bf(v.z); s4.w = f2bf(v.w);
            *(ushort4*)&As[m * LD + q * 4] = s4;
        }
        // stage B: M rows(n) x 64 k bf16 (uint4 = 8 bf16)
#pragma unroll
        for (int j = 0; j < M * 8 / 256; ++j) {
            int idx = tid + j * 256;
            int nn = idx >> 3;
            int q = idx & 7;
            uint4 v = *(const uint4*)&Wt[(size_t)nn * K + k0 + q * 8];
            *(uint4*)&Bs[nn * LD + q * 8] = v;
        }
        __syncthreads();
#pragma unroll
        for (int ks = 0; ks < BK / 32; ++ks) {
            bf16x8 af[4], bfr[NT];
#pragma unroll
            for (int nt = 0; nt < NT; ++nt)
                bfr[nt] = *(const bf16x8*)&Bs[(n0 + nt * 16 + r16) * LD + ks * 32 + quad * 8];
#pragma unroll
            for (int mt = 0; mt < 4; ++mt)
                af[mt] = *(const bf16x8*)&As[(mt * 16 + r16) * LD + ks * 32 + quad * 8];
#pragma unroll
            for (int mt = 0; mt < 4; ++mt)
#pragma unroll
                for (int nt = 0; nt < NT; ++nt)
                    acc[mt][nt] = __builtin_amdgcn_mfma_f32_16x16x32_bf16(
                        af[mt], bfr[nt], acc[mt][nt], 0, 0, 0);
        }
        __syncthreads();
    }
    // epilogue: scale, bf16, LDS transpose-stage for coalesced stores
    unsigned short* Cs = smem;                // [64][CLD]
#pragma unroll
    for (int mt = 0; mt < 4; ++mt) {
#pragma unroll
        for (int i = 0; i < 4; ++i) {
            int r = mt * 16 + quad * 4 + i;
            float sc = sdv[r];
#pragma unroll
            for (int nt = 0; nt < NT; ++nt)
                Cs[r * CLD + n0 + nt * 16 + r16] = f2bf(acc[mt][nt][i] * sc);
        }
    }
    __syncthreads();
#pragma unroll
    for (int j = 0; j < 64 * M / 8 / 256; ++j) {
        int idx = tid + j * 256;
        int r = idx / (M / 8);
        int q = idx % (M / 8);
        int gr = row0 + r;
        if (gr < N) {
            uint4 v = *(const uint4*)&Cs[r * CLD + q * 8];
            *(uint4*)&C[(size_t)gr * M + q * 8] = v;
        }
    }
}

// Layer-1 aggregation: 1 wave/node, half-wave edge split.
// Lane: half = lane>>5 (edge slot), sub = lane&31 (features 4sub..4sub+3).
// 2 edges/step x4 unroll = 8 gathers in flight.
__launch_bounds__(256)
__global__ void agg1_kernel(const uint2* __restrict__ xw,        // bf16 [n][128] (pre-scaled)
                            const int* __restrict__ rowptr,
                            const int2* __restrict__ edge,       // (src, raw w)
                            const float* __restrict__ dinv,
                            const float* __restrict__ bias,      // fp32 [128]
                            float* __restrict__ out, int n) {    // fp32 [n][128]
    int node = blockIdx.x * 4 + (threadIdx.x >> 6);
    if (node >= n) return;
    int lane = threadIdx.x & 63;
    int half = lane >> 5, sub = lane & 31;
    float a0 = 0.f, a1 = 0.f, a2 = 0.f, a3 = 0.f;
    if (half == 0) {
        uint2 u = xw[(size_t)node * 32 + sub];
        a0 = bflo(u.x); a1 = bfhi(u.x); a2 = bflo(u.y); a3 = bfhi(u.y);
    }
    int p = rowptr[node], p1 = rowptr[node + 1];
    for (; p + 8 <= p1; p += 8) {
        int2 e0 = edge[p + half],     e1 = edge[p + 2 + half];
        int2 e2 = edge[p + 4 + half], e3 = edge[p + 6 + half];
        uint2 v0 = xw[(size_t)e0.x * 32 + sub];
        uint2 v1 = xw[(size_t)e1.x * 32 + sub];
        uint2 v2 = xw[(size_t)e2.x * 32 + sub];
        uint2 v3 = xw[(size_t)e3.x * 32 + sub];
        float w0 = __int_as_float(e0.y), w1 = __int_as_float(e1.y);
        float w2 = __int_as_float(e2.y), w3 = __int_as_float(e3.y);
        a0 += w0 * bflo(v0.x) + w1 * bflo(v1.x) + w2 * bflo(v2.x) + w3 * bflo(v3.x);
        a1 += w0 * bfhi(v0.x) + w1 * bfhi(v1.x) + w2 * bfhi(v2.x) + w3 * bfhi(v3.x);
        a2 += w0 * bflo(v0.y) + w1 * bflo(v1.y) + w2 * bflo(v2.y) + w3 * bflo(v3.y);
        a3 += w0 * bfhi(v0.y) + w1 * bfhi(v1.y) + w2 * bfhi(v2.y) + w3 * bfhi(v3.y);
    }
    for (; p + 2 <= p1; p += 2) {
        int2 e0 = edge[p + half];
        uint2 v0 = xw[(size_t)e0.x * 32 + sub];
        float w0 = __int_as_float(e0.y);
        a0 += w0 * bflo(v0.x); a1 += w0 * bfhi(v0.x);
        a2 += w0 * bflo(v0.y); a3 += w0 * bfhi(v0.y);
    }
    if (p < p1 && half == 0) {
        int2 e0 = edge[p];
        uint2 v0 = xw[(size_t)e0.x * 32 + sub];
        float w0 = __int_as_float(e0.y);
        a0 += w0 * bflo(v0.x); a1 += w0 * bfhi(v0.x);
        a2 += w0 * bflo(v0.y); a3 += w0 * bfhi(v0.y);
    }
    a0 += __shfl_xor(a0, 32); a1 += __shfl_xor(a1, 32);
    a2 += __shfl_xor(a2, 32); a3 += __shfl_xor(a3, 32);
    float di = dinv[node];
    float4 b = ((const float4*)bias)[sub];
    a0 = fmaxf(di * a0 + b.x, 0.f);
    a1 = fmaxf(di * a1 + b.y, 0.f);
    a2 = fmaxf(di * a2 + b.z, 0.f);
    a3 = fmaxf(di * a3 + b.w, 0.f);
    if (half == 0)
        ((float4*)out)[(size_t)node * 32 + sub] = make_float4(a0, a1, a2, a3);
}

// Layer-2 aggregation + log_softmax: 1 wave/node, quarter-wave edge split.
// Lane: qw = lane>>4 (edge slot), sub = lane&15 (features 4sub..4sub+3).
// 4 edges/step x2 unroll = 8 gathers in flight.
__launch_bounds__(256)
__global__ void agg2_kernel(const uint2* __restrict__ xw,        // bf16 [n][64] (pre-scaled)
                            const int* __restrict__ rowptr,
                            const int2* __restrict__ edge,
                            const float* __restrict__ dinv,
                            const float* __restrict__ bias,      // fp32 [64]
                            float* __restrict__ out, int n) {    // fp32 [n][64]
    int node = blockIdx.x * 4 + (threadIdx.x >> 6);
    if (node >= n) return;
    int lane = threadIdx.x & 63;
    int qw = lane >> 4, sub = lane & 15;
    float a0 = 0.f, a1 = 0.f, a2 = 0.f, a3 = 0.f;
    if (qw == 0) {
        uint2 u = xw[(size_t)node * 16 + sub];
        a0 = bflo(u.x); a1 = bfhi(u.x); a2 = bflo(u.y); a3 = bfhi(u.y);
    }
    int p = rowptr[node], p1 = rowptr[node + 1];
    for (; p + 8 <= p1; p += 8) {
        int2 e0 = edge[p + qw], e1 = edge[p + 4 + qw];
        uint2 v0 = xw[(size_t)e0.x * 16 + sub];
        uint2 v1 = xw[(size_t)e1.x * 16 + sub];
        float w0 = __int_as_float(e0.y), w1 = __int_as_float(e1.y);
        a0 += w0 * bflo(v0.x) + w1 * bflo(v1.x);
        a1 += w0 * bfhi(v0.x) + w1 * bfhi(v1.x);
        a2 += w0 * bflo(v0.y) + w1 * bflo(v1.y);
        a3 += w0 * bfhi(v0.y) + w1 * bfhi(v1.y);
    }
    for (; p + 4 <= p1; p += 4) {
        int2 e0 = edge[p + qw];
        uint2 v0 = xw[(size_t)e0.x * 16 + sub];
        float w0 = __int_as_float(e0.y);
        a0 += w0 * bflo(v0.x); a1 += w0 * bfhi(v0.x);
        a2 += w0 * bflo(v0.y); a3 += w0 * bfhi(v0.y);
    }
    int rem = p1 - p;
    if (qw < rem) {
        int2 e0 = edge[p + qw];
        uint2 v0 = xw[(size_t)e0.x * 16 + sub];
        float w0 = __int_as_float(e0.y);
        a0 += w0 * bflo(v0.x); a1 += w0 * bfhi(v0.x);
        a2 += w0 * bflo(v0.y); a3 += w0 * bfhi(v0.y);
    }
    a0 += __shfl_xor(a0, 32); a1 += __shfl_xor(a1, 32);
    a2 += __shfl_xor(a2, 32); a3 += __shfl_xor(a3, 32);
    a0 += __shfl_xor(a0, 16); a1 += __shfl_xor(a1, 16);
    a2 += __shfl_xor(a2, 16); a3 += __shfl_xor(a3, 16);
    float di = dinv[node];
    float4 b = ((const float4*)bias)[sub];
    a0 = di * a0 + b.x; a1 = di * a1 + b.y;
    a2 = di * a2 + b.z; a3 = di * a3 + b.w;
    float m = fmaxf(fmaxf(a0, a1), fmaxf(a2, a3));
#pragma unroll
    for (int off = 8; off > 0; off >>= 1) m = fmaxf(m, __shfl_xor(m, off));
    float s = __expf(a0 - m) + __expf(a1 - m) + __expf(a2 - m) + __expf(a3 - m);
#pragma unroll
    for (int off = 8; off > 0; off >>= 1) s += __shfl_xor(s, off);
    float lse = m + __logf(s);
    if (qw == 0)
        ((float4*)out)[(size_t)node * 16 + sub] =
            make_float4(a0 - lse, a1 - lse, a2 - lse, a3 - lse);
}

extern "C" void kernel_launch(void* const* d_in, const int* in_sizes, int n_in,
                              void* d_out, int out_size, void* d_ws, size_t ws_size,
                              hipStream_t stream) {
    const float* x  = (const float*)d_in[0];
    const int*   ei = (const int*)d_in[1];
    const float* ew = (const float*)d_in[2];
    const float* W1 = (const float*)d_in[3];
    const float* b1 = (const float*)d_in[4];
    const float* W2 = (const float*)d_in[5];
    const float* b2 = (const float*)d_in[6];
    float* out = (float*)d_out;

    const int n = in_sizes[0] / DIN;      // 50000
    const int E = in_sizes[2];            // 1600000
    const int* row = ei;                  // edge_index[0] (source)
    const int* col = ei + E;              // edge_index[1] (target)

    const int NB = (n + NPB - 1) / NPB;   // 500 buckets
    const int P  = NB;
    const int Ec = (E + P - 1) / P;       // 3200 edges/block

    char* ptr = (char*)d_ws;
    auto alloc = [&](size_t bytes) -> void* {
        void* r = (void*)ptr;
        ptr += (bytes + 255) & ~(size_t)255;
        return r;
    };
    int*   bh     = (int*)  alloc((size_t)P * NB * 4);       // 1 MB
    int*   btotal = (int*)  alloc((size_t)NB * 4);
    int*   bbase  = (int*)  alloc((size_t)(NB + 1) * 4);
    int*   rowptr = (int*)  alloc((size_t)(n + 1) * 4);
    float* dinv   = (float*)alloc((size_t)n * 4);
    int2*  edge   = (int2*) alloc((size_t)E * 8);            // CSR edges (src, raw w)
    unsigned short* xw1 = (unsigned short*)alloc((size_t)n * DH * 2);  // bf16 tables
    unsigned short* wt1 = (unsigned short*)alloc((size_t)DH * DIN * 2);
    unsigned short* wt2 = (unsigned short*)alloc((size_t)DOUT * DH * 2);
    // tail: part (12.8MB, build phase) then h1 (25.6MB, compute phase)
    char* tail = (char*)alloc((size_t)n * DH * 4);
    int2*  part = (int2*)tail;
    float* h1   = (float*)tail;
    unsigned short* xw2 = xw1;            // layer-2 table aliases layer-1 table

    const int nb_g = (n + 63) / 64;       // 782
    const int nb_a = (n + 3) / 4;         // 12500

    prep_w_kernel<<<(DH * DIN + DOUT * DH + 255) / 256, 256, 0, stream>>>(W1, W2, wt1, wt2);
    hist_kernel<<<P, 256, 0, stream>>>(col, bh, E, Ec, NB);
    colscan_kernel<<<NB, 512, 0, stream>>>(bh, btotal, P, NB);
    basescan_kernel<<<1, 512, 0, stream>>>(btotal, bbase, rowptr, NB, n, E);
    scatter_kernel<<<P, 256, 0, stream>>>(row, col, ew, bh, bbase, part, E, Ec, NB);
    bucket_csr_kernel<<<NB, 256, 0, stream>>>(part, bbase, dinv, rowptr, edge, n);

    gemm_mfma_kernel<DIN, DH><<<nb_g, 256, 0, stream>>>(x, wt1, dinv, xw1, n);
    agg1_kernel<<<nb_a, 256, 0, stream>>>((const uint2*)xw1, rowptr, edge, dinv, b1, h1, n);
    gemm_mfma_kernel<DH, DOUT><<<nb_g, 256, 0, stream>>>(h1, wt2, dinv, xw2, n);
    agg2_kernel<<<nb_a, 256, 0, stream>>>((const uint2*)xw2, rowptr, edge, dinv, b2, out, n);
}